// Round 9
// baseline (647.115 us; speedup 1.0000x reference)
//
#include <hip/hip_runtime.h>
#include <hip/hip_bf16.h>
#include <hip/hip_cooperative_groups.h>

namespace cg = cooperative_groups;

// GCN layer: out[c] = bias + dis[c]*(hs[c] + sum_{r in in(c)} hs[r]),
//            hs = (X @ W) * dis[row]  (bf16), dis = rsqrt(deg+1).
// N=50000, E=800000, D=64, fp32 in/out.
// R9: ONE cooperative kernel (was 6 dispatches). Phases separated by grid.sync():
//   P1 u8 histograms (256 jobs) -> P2 reduce+dis+block scan (scan state stays in
//   registers) -> P3 partials scan + offs + u8 rel starts -> P4 bucket(160 blk)
//   CONCURRENT with gemm(96 blk) -> P5 gather. offs has sentinel (no cnt array).

constexpr int N_NODES = 50000;
constexpr int N_EDGES = 800000;
constexpr int D = 64;

constexpr int NBLK = 256;
constexpr int NTHR = 1024;
constexpr int B_SLICE = 128;                    // edge slices
constexpr int SLICE = N_EDGES / B_SLICE;        // 6250
constexpr int PACK8 = N_NODES / 4;              // 12500 u32 words (u8 x4)
constexpr int QUAR = N_NODES / 4;               // 12500 nodes per bucket quarter
constexpr int CHUNK = (N_NODES + NBLK - 1) / NBLK;  // 196 nodes per block
constexpr int GEMM_BLOCKS = 96;
constexpr int NTILES = (N_NODES + 127) / 128;   // 391

static __device__ __forceinline__ unsigned short f2bf(float f) {
    unsigned u = __float_as_uint(f);
    unsigned r = (u + 0x7fffu + ((u >> 16) & 1u)) >> 16;  // RNE
    return (unsigned short)r;
}
static __device__ __forceinline__ float bf2f(unsigned short s) {
    return __uint_as_float((unsigned)s << 16);
}

// =========================== fused cooperative kernel ===========================
__global__ __launch_bounds__(NTHR, 4) void fused_kernel(
    const int* __restrict__ ei, const float* __restrict__ x,
    const float* __restrict__ Wm, const float* __restrict__ bias,
    float* __restrict__ out, float* __restrict__ dis, int* __restrict__ offs,
    int* __restrict__ csr, unsigned short* __restrict__ hs,
    unsigned* __restrict__ bh, unsigned char* __restrict__ bs8,
    int* __restrict__ partials)
{
    cg::grid_group grid = cg::this_grid();
    __shared__ __align__(16) unsigned char smem[51200];  // union across phases
    const int b = blockIdx.x;
    const int t = threadIdx.x;

    // ---------- P1: per-slice u8-packed histograms; 256 jobs = 128 slices x {row,col}
    {
        unsigned* loc = (unsigned*)smem;  // 50 KB
        for (int w = t; w < PACK8; w += NTHR) loc[w] = 0;
        __syncthreads();
        const int* arr = (b < B_SLICE) ? ei : (ei + N_EDGES);
        const int* p = arr + (b & (B_SLICE - 1)) * SLICE;
        for (int i = t; i < SLICE; i += NTHR) {
            int k = p[i];
            atomicAdd(&loc[k >> 2], 1u << (8 * (k & 3)));  // LDS atomic, max ~5/bin
        }
        __syncthreads();
        unsigned* dst = bh + (size_t)b * PACK8;
        for (int w = t; w < PACK8; w += NTHR) dst[w] = loc[w];
    }
    grid.sync();

    // ---------- P2: reduce degrees/counts, dis, block-local scan (state in regs)
    int myex = 0;        // exclusive prefix within chunk -- persists to P3
    unsigned mycl = 0;
    {
        const int i = b * CHUNK + t;
        const bool act = (t < CHUNK) && (i < N_NODES);
        if (act) {
            const int w = i >> 2;
            const unsigned sh = 8 * (i & 3);
            const unsigned* prow = bh + w;
            const unsigned* pcol = bh + (size_t)B_SLICE * PACK8 + w;
            unsigned dl = 0, cl = 0;
            for (int g = 0; g < B_SLICE / 16; ++g) {
                unsigned vr[16];
#pragma unroll
                for (int k = 0; k < 16; ++k) vr[k] = prow[(size_t)(g * 16 + k) * PACK8];
#pragma unroll
                for (int k = 0; k < 16; ++k) dl += (vr[k] >> sh) & 0xffu;
            }
            for (int g = 0; g < B_SLICE / 16; ++g) {
                unsigned vr[16];
#pragma unroll
                for (int k = 0; k < 16; ++k) vr[k] = pcol[(size_t)(g * 16 + k) * PACK8];
#pragma unroll
                for (int k = 0; k < 16; ++k) cl += (vr[k] >> sh) & 0xffu;
            }
            mycl = cl;
            dis[i] = rsqrtf((float)dl + 1.0f);  // +1 self loop
        }
        int* s = (int*)smem;
        if (t < 256) s[t] = (t < CHUNK) ? (int)mycl : 0;
        __syncthreads();
        for (int d = 1; d < 256; d <<= 1) {
            int u = 0;
            if (t < 256 && t >= d) u = s[t - d];
            __syncthreads();
            if (t < 256) s[t] += u;
            __syncthreads();
        }
        if (t < CHUNK) myex = s[t] - (int)mycl;
        if (t == 255) partials[b] = s[255];
    }
    grid.sync();

    // ---------- P3: redundant partials scan + absolute offs + u8 relative starts
    {
        int* pref = (int*)smem;
        if (t < 256) pref[t] = partials[t];
        __syncthreads();
        for (int d = 1; d < 256; d <<= 1) {
            int u = 0;
            if (t < 256 && t >= d) u = pref[t - d];
            __syncthreads();
            if (t < 256) pref[t] += u;
            __syncthreads();
        }
        const int base = (b == 0) ? 0 : pref[b - 1];
        const int i = b * CHUNK + t;
        if (t < CHUNK && i < N_NODES) {
            offs[i] = base + myex;
            const int w = i >> 2;
            const unsigned sh = 8 * (i & 3);
            const unsigned* pcol = bh + (size_t)B_SLICE * PACK8 + w;
            unsigned rel = 0;
            for (int g = 0; g < B_SLICE / 16; ++g) {
                unsigned vr[16];
#pragma unroll
                for (int k = 0; k < 16; ++k) vr[k] = pcol[(size_t)(g * 16 + k) * PACK8];
#pragma unroll
                for (int k = 0; k < 16; ++k) {
                    bs8[(size_t)(g * 16 + k) * N_NODES + i] = (unsigned char)rel;
                    rel += (vr[k] >> sh) & 0xffu;
                }
            }
        }
        if (b == 0 && t == 0) offs[N_NODES] = N_EDGES;  // sentinel
        __syncthreads();
    }
    grid.sync();

    // ---------- P4: gemm (96 blocks) CONCURRENT with bucket (160 blocks)
    if (b < GEMM_BLOCKS) {
        float* Xs = (float*)smem;             // [128][68] = 34816 B
        float* Ws = (float*)(smem + 34816);   // [64][64]  = 16384 B
        ((float4*)Ws)[t] = ((const float4*)Wm)[t];  // 1024 float4 = whole W
        for (int tile = b; tile < NTILES; tile += GEMM_BLOCKS) {
            const int n0 = tile * 128;
#pragma unroll
            for (int i2 = 0; i2 < 2; ++i2) {
                int f = t + i2 * NTHR;           // 0..2047 float4s
                int r = f >> 4, c = (f & 15) << 2;
                float4 v = make_float4(0.f, 0.f, 0.f, 0.f);
                if (n0 + r < N_NODES) v = ((const float4*)x)[(size_t)n0 * 16 + f];
                float* dstp = Xs + r * 68 + c;
                dstp[0] = v.x; dstp[1] = v.y; dstp[2] = v.z; dstp[3] = v.w;
            }
            __syncthreads();
            const int tx = t & 15, ty = t >> 4;  // ty 0..63: rows ty*2, ty*2+1
            float acc[2][4] = {};
#pragma unroll
            for (int k = 0; k < D; ++k) {
                float a0 = Xs[(ty * 2) * 68 + k];
                float a1 = Xs[(ty * 2 + 1) * 68 + k];
                const float* wrow = Ws + k * 64 + tx * 4;
#pragma unroll
                for (int jj = 0; jj < 4; ++jj) {
                    float bb = wrow[jj];
                    acc[0][jj] = fmaf(a0, bb, acc[0][jj]);
                    acc[1][jj] = fmaf(a1, bb, acc[1][jj]);
                }
            }
#pragma unroll
            for (int i2 = 0; i2 < 2; ++i2) {
                int n = n0 + ty * 2 + i2;
                if (n < N_NODES) {
                    float dr = dis[n];
                    ushort4 v;
                    v.x = f2bf(acc[i2][0] * dr); v.y = f2bf(acc[i2][1] * dr);
                    v.z = f2bf(acc[i2][2] * dr); v.w = f2bf(acc[i2][3] * dr);
                    *(ushort4*)(hs + (size_t)n * D + tx * 4) = v;
                }
            }
            __syncthreads();
        }
    } else {
        unsigned* pos = (unsigned*)smem;  // 50 KB
        for (int j = b - GEMM_BLOCKS; j < 4 * B_SLICE; j += NBLK - GEMM_BLOCKS) {
            const int s = j >> 2, q = j & 3;
            const int c0 = q * QUAR;
            const int* offq = offs + c0;
            const unsigned char* relq = bs8 + (size_t)s * N_NODES + c0;
            for (int w = t; w < QUAR; w += NTHR)
                pos[w] = (unsigned)offq[w] + relq[w];
            __syncthreads();
            const int* rowp = ei + s * SLICE;
            const int* colp = ei + N_EDGES + s * SLICE;
            for (int i = t; i < SLICE; i += NTHR) {
                int c = colp[i];
                if (c >= c0 && c < c0 + QUAR) {
                    unsigned p = atomicAdd(&pos[c - c0], 1u);  // LDS atomic
                    csr[p] = rowp[i];
                }
            }
            __syncthreads();
        }
    }
    grid.sync();

    // ---------- P5: gather (wave per node, grid-strided; MLP 16)
    {
        const int wave = (b << 4) + (t >> 6);  // 0..4095
        const int j = t & 63;
        const float bj = bias[j];
        for (int n = wave; n < N_NODES; n += NBLK * 16) {
            float a[8];
            a[0] = bf2f(hs[(size_t)n * D + j]);  // self loop (dis[n]*h[n])
#pragma unroll
            for (int k = 1; k < 8; ++k) a[k] = 0.f;
            int beg = __builtin_amdgcn_readfirstlane(offs[n]);
            int m   = __builtin_amdgcn_readfirstlane(offs[n + 1]) - beg;
            const int* p = csr + beg;
            int i = 0;
            for (; i + 16 <= m; i += 16) {
                int r[16];
                float v[16];
#pragma unroll
                for (int k = 0; k < 16; ++k) r[k] = p[i + k];
#pragma unroll
                for (int k = 0; k < 16; ++k) v[k] = bf2f(hs[(size_t)r[k] * D + j]);
#pragma unroll
                for (int k = 0; k < 16; ++k) a[k & 7] += v[k];
            }
            for (; i + 4 <= m; i += 4) {
                int r0 = p[i], r1 = p[i + 1], r2 = p[i + 2], r3 = p[i + 3];
                a[0] += bf2f(hs[(size_t)r0 * D + j]);
                a[1] += bf2f(hs[(size_t)r1 * D + j]);
                a[2] += bf2f(hs[(size_t)r2 * D + j]);
                a[3] += bf2f(hs[(size_t)r3 * D + j]);
            }
            for (; i < m; ++i) a[1] += bf2f(hs[(size_t)p[i] * D + j]);
            float tot = ((a[0] + a[1]) + (a[2] + a[3])) + ((a[4] + a[5]) + (a[6] + a[7]));
            out[(size_t)n * D + j] = fmaf(dis[n], tot, bj);
        }
    }
}

// =========================== fallback (atomic) path ===========================

__global__ void hist_kernel(const int* __restrict__ row, const int* __restrict__ col,
                            int* __restrict__ degi, int* __restrict__ cnt) {
    int e = blockIdx.x * blockDim.x + threadIdx.x;
    if (e < N_EDGES) {
        atomicAdd(&degi[row[e]], 1);
        atomicAdd(&cnt[col[e]], 1);
    }
}

__global__ void dis_kernel(int* __restrict__ degi) {
    int i = blockIdx.x * blockDim.x + threadIdx.x;
    if (i < N_NODES) {
        float d = (float)degi[i] + 1.0f;
        ((float*)degi)[i] = rsqrtf(d);
    }
}

__global__ void bucket_kernel(const int* __restrict__ row, const int* __restrict__ col,
                              const int* __restrict__ offs, int* __restrict__ cur,
                              int* __restrict__ csr) {
    int e = blockIdx.x * blockDim.x + threadIdx.x;
    if (e < N_EDGES) {
        int c = col[e];
        int pos = offs[c] + atomicAdd(&cur[c], 1);
        csr[pos] = row[e];
    }
}

constexpr int NB_SCAN = (N_NODES + 255) / 256;  // 196

__global__ void block_scan_kernel(const int* __restrict__ cnt, int* __restrict__ offs,
                                  int* __restrict__ partials) {
    __shared__ int s[256];
    int t = threadIdx.x;
    int i = blockIdx.x * 256 + t;
    int v = (i < N_NODES) ? cnt[i] : 0;
    s[t] = v;
    __syncthreads();
    for (int d = 1; d < 256; d <<= 1) {
        int u = (t >= d) ? s[t - d] : 0;
        __syncthreads();
        s[t] += u;
        __syncthreads();
    }
    if (i < N_NODES) offs[i] = s[t] - v;
    if (t == 255) partials[blockIdx.x] = s[t];
}

__global__ void scan_partials_kernel(int* __restrict__ partials) {
    __shared__ int s[256];
    int t = threadIdx.x;
    int v = (t < NB_SCAN) ? partials[t] : 0;
    s[t] = v;
    __syncthreads();
    for (int d = 1; d < 256; d <<= 1) {
        int u = (t >= d) ? s[t - d] : 0;
        __syncthreads();
        s[t] += u;
        __syncthreads();
    }
    if (t < NB_SCAN) partials[t] = s[t] - v;
}

__global__ void add_off_kernel(int* __restrict__ offs, const int* __restrict__ partials) {
    int i = blockIdx.x * 256 + threadIdx.x;
    if (i < N_NODES) offs[i] += partials[blockIdx.x];
    if (i == 0) offs[N_NODES] = N_EDGES;
}

__global__ __launch_bounds__(256) void gemm_sa_kernel(const float* __restrict__ x,
                                                      const float* __restrict__ W,
                                                      const float* __restrict__ dis,
                                                      unsigned short* __restrict__ hs) {
    __shared__ float Xs[64][68];
    __shared__ float Ws[64][64];
    int t = threadIdx.x;
    int n0 = blockIdx.x * 64;
    const float4* W4 = (const float4*)W;
    float4* Ws4 = (float4*)Ws;
#pragma unroll
    for (int i = 0; i < 4; ++i) Ws4[t + i * 256] = W4[t + i * 256];
    const float4* x4 = (const float4*)(x + (size_t)n0 * D);
#pragma unroll
    for (int i = 0; i < 4; ++i) {
        int f = t + i * 256;
        int r = f >> 4;
        int c = (f & 15) << 2;
        float4 v = make_float4(0.f, 0.f, 0.f, 0.f);
        if (n0 + r < N_NODES) v = x4[f];
        Xs[r][c] = v.x; Xs[r][c + 1] = v.y; Xs[r][c + 2] = v.z; Xs[r][c + 3] = v.w;
    }
    __syncthreads();
    int tx = t & 15, ty = t >> 4;
    float acc[4][4] = {};
#pragma unroll
    for (int k = 0; k < D; ++k) {
        float a[4], bb[4];
#pragma unroll
        for (int i = 0; i < 4; ++i) a[i] = Xs[ty * 4 + i][k];
#pragma unroll
        for (int jj = 0; jj < 4; ++jj) bb[jj] = Ws[k][tx * 4 + jj];
#pragma unroll
        for (int i = 0; i < 4; ++i)
#pragma unroll
            for (int jj = 0; jj < 4; ++jj)
                acc[i][jj] = fmaf(a[i], bb[jj], acc[i][jj]);
    }
#pragma unroll
    for (int i = 0; i < 4; ++i) {
        int r = ty * 4 + i;
        if (n0 + r < N_NODES) {
            float dr = dis[n0 + r];
            ushort4 v;
            v.x = f2bf(acc[i][0] * dr); v.y = f2bf(acc[i][1] * dr);
            v.z = f2bf(acc[i][2] * dr); v.w = f2bf(acc[i][3] * dr);
            *(ushort4*)(hs + (size_t)(n0 + r) * D + tx * 4) = v;
        }
    }
}

__global__ __launch_bounds__(256) void gather_sa_kernel(const int* __restrict__ offs,
                                                        const int* __restrict__ csr,
                                                        const unsigned short* __restrict__ hs,
                                                        const float* __restrict__ dis,
                                                        const float* __restrict__ bias,
                                                        float* __restrict__ out) {
    int wave = threadIdx.x >> 6;
    int j = threadIdx.x & 63;
    int n = blockIdx.x * 4 + wave;
    if (n >= N_NODES) return;
    float a[8];
    a[0] = bf2f(hs[(size_t)n * D + j]);
#pragma unroll
    for (int k = 1; k < 8; ++k) a[k] = 0.f;
    int beg = __builtin_amdgcn_readfirstlane(offs[n]);
    int m   = __builtin_amdgcn_readfirstlane(offs[n + 1]) - beg;
    const int* p = csr + beg;
    int i = 0;
    for (; i + 16 <= m; i += 16) {
        int r[16];
        float v[16];
#pragma unroll
        for (int k = 0; k < 16; ++k) r[k] = p[i + k];
#pragma unroll
        for (int k = 0; k < 16; ++k) v[k] = bf2f(hs[(size_t)r[k] * D + j]);
#pragma unroll
        for (int k = 0; k < 16; ++k) a[k & 7] += v[k];
    }
    for (; i + 4 <= m; i += 4) {
        int r0 = p[i], r1 = p[i + 1], r2 = p[i + 2], r3 = p[i + 3];
        a[0] += bf2f(hs[(size_t)r0 * D + j]);
        a[1] += bf2f(hs[(size_t)r1 * D + j]);
        a[2] += bf2f(hs[(size_t)r2 * D + j]);
        a[3] += bf2f(hs[(size_t)r3 * D + j]);
    }
    for (; i < m; ++i) a[1] += bf2f(hs[(size_t)p[i] * D + j]);
    float tot = ((a[0] + a[1]) + (a[2] + a[3])) + ((a[4] + a[5]) + (a[6] + a[7]));
    out[(size_t)n * D + j] = fmaf(dis[n], tot, bias[j]);
}

// =========================== launch ===========================

extern "C" void kernel_launch(void* const* d_in, const int* in_sizes, int n_in,
                              void* d_out, int out_size, void* d_ws, size_t ws_size,
                              hipStream_t stream) {
    const int*   ei   = (const int*)d_in[1];
    const float* x    = (const float*)d_in[0];
    const float* W    = (const float*)d_in[2];
    const float* bias = (const float*)d_in[3];
    float* out = (float*)d_out;

    // fused layout (bytes):
    //   [0        ..   200000)  dis
    //   [200000   ..   400064)  offs (N+1 ints, padded)
    //   [400064   ..   401088)  partials (256 ints)
    //   [401088   ..  3601088)  csr (800000 x int)
    //   [3601088  .. 10001088)  hs (50000 x 64 bf16)
    //   [10001088 .. 22801088)  bh (256 x 12500 u32, u8-packed)
    //   [22801088 .. 29201088)  bs8 (128 x 50000 u8)
    char* ws = (char*)d_ws;
    float*          dis      = (float*)(ws + 0);
    int*            offs     = (int*)(ws + 200000);
    int*            partials = (int*)(ws + 400064);
    int*            csr      = (int*)(ws + 401088);
    unsigned short* hs       = (unsigned short*)(ws + 3601088);
    unsigned*       bh       = (unsigned*)(ws + 10001088);
    unsigned char*  bs8      = (unsigned char*)(ws + 22801088);

    const size_t WS_NEEDED = 29201088;

    if (ws_size >= WS_NEEDED) {
        void* args[] = {(void*)&ei, (void*)&x, (void*)&W, (void*)&bias, (void*)&out,
                        (void*)&dis, (void*)&offs, (void*)&csr, (void*)&hs,
                        (void*)&bh, (void*)&bs8, (void*)&partials};
        hipLaunchCooperativeKernel((void*)fused_kernel, dim3(NBLK), dim3(NTHR),
                                   args, 0, stream);
    } else {
        // fallback layout: degi 0, cnt 200000, cur 400000, offs 600000, partials 800064,
        // csr 801088, hs 4001088, then done (no bh/bs8 needed)
        int*            degi  = (int*)(ws + 0);
        int*            cntf  = (int*)(ws + 200000);
        int*            curf  = (int*)(ws + 400000);
        int*            offsf = (int*)(ws + 600000);
        int*            partf = (int*)(ws + 800064);
        int*            csrf  = (int*)(ws + 801088);
        unsigned short* hsf   = (unsigned short*)(ws + 4001088);
        float*          disf  = (float*)degi;
        const int* row = ei;
        const int* col = ei + N_EDGES;
        hipMemsetAsync(ws, 0, 600000, stream);
        hist_kernel<<<(N_EDGES + 255) / 256, 256, 0, stream>>>(row, col, degi, cntf);
        dis_kernel<<<(N_NODES + 255) / 256, 256, 0, stream>>>(degi);
        block_scan_kernel<<<NB_SCAN, 256, 0, stream>>>(cntf, offsf, partf);
        scan_partials_kernel<<<1, 256, 0, stream>>>(partf);
        add_off_kernel<<<NB_SCAN, 256, 0, stream>>>(offsf, partf);
        bucket_kernel<<<(N_EDGES + 255) / 256, 256, 0, stream>>>(row, col, offsf, curf, csrf);
        gemm_sa_kernel<<<(N_NODES + 63) / 64, 256, 0, stream>>>(x, W, disf, hsf);
        gather_sa_kernel<<<(N_NODES + 3) / 4, 256, 0, stream>>>(offsf, csrf, hsf, disf, bias, out);
    }
}

// Round 10
// 363.917 us; speedup vs baseline: 1.7782x; 1.7782x over previous
//
#include <hip/hip_runtime.h>
#include <hip/hip_bf16.h>

// GCN layer: out[c] = bias + h[c]*dis[c]^2 + sum_{e: col=c} h[row_e]*dis[row_e]*dis[c]
//            h = X @ W (bf16, unscaled), dis = rsqrt(deg+1).
// N=50000, E=800000, D=64, fp32 in/out.
// R10: revert R9 mega-fusion (VGPR-capped spill -> 836MB scratch traffic).
//      5 dispatches: [hist || gemm] -> reduce_scan(+bs8 inline) -> offs -> bucket -> gather.
//      h unscaled so gemm is independent of build; csr = int2{row, norm}.

constexpr int N_NODES = 50000;
constexpr int N_EDGES = 800000;
constexpr int D = 64;
constexpr int NB_SCAN = (N_NODES + 255) / 256;  // 196

constexpr int B_SLICE = 64;                  // edge slices
constexpr int SLICE = N_EDGES / B_SLICE;     // 12500 (exact)
constexpr int PACK8 = N_NODES / 4;           // 12500 u32 words (u8 x4)
constexpr int QUAR = N_NODES / 4;            // 12500 nodes per bucket quarter
constexpr int HIST_BLOCKS = 2 * B_SLICE;     // 128
constexpr int GEMM_TILE = 128;
constexpr int NTILES = (N_NODES + GEMM_TILE - 1) / GEMM_TILE;  // 391

static __device__ __forceinline__ unsigned short f2bf(float f) {
    unsigned u = __float_as_uint(f);
    unsigned r = (u + 0x7fffu + ((u >> 16) & 1u)) >> 16;  // RNE
    return (unsigned short)r;
}
static __device__ __forceinline__ float bf2f(unsigned short s) {
    return __uint_as_float((unsigned)s << 16);
}

// ---- 1. fused dispatch: blocks [0,128) u8 histograms; blocks [128,519) gemm ----
// No launch-bounds min-occupancy arg: let the compiler take the VGPRs it needs
// (R9 lesson: forced 64-VGPR cap spilled the batch arrays to scratch).
__global__ __launch_bounds__(1024) void histgemm_kernel(const int* __restrict__ ei,
                                                        const float* __restrict__ x,
                                                        const float* __restrict__ Wm,
                                                        unsigned* __restrict__ bh,
                                                        unsigned short* __restrict__ h) {
    __shared__ __align__(16) unsigned char smem[51200];
    const int b = blockIdx.x;
    const int t = threadIdx.x;

    if (b < HIST_BLOCKS) {
        // per-slice u8-packed histogram (Poisson(0.25)/bin -> u8 never overflows)
        unsigned* loc = (unsigned*)smem;  // 50 KB
        for (int w = t; w < PACK8; w += 1024) loc[w] = 0;
        __syncthreads();
        const int* arr = (b < B_SLICE) ? ei : ei + N_EDGES;  // row : col
        const int* p = arr + (b & (B_SLICE - 1)) * SLICE;
        for (int i = t; i < SLICE; i += 1024) {
            int k = p[i];
            atomicAdd(&loc[k >> 2], 1u << (8 * (k & 3)));  // LDS atomic
        }
        __syncthreads();
        unsigned* dst = bh + (size_t)b * PACK8;
        for (int w = t; w < PACK8; w += 1024) dst[w] = loc[w];
    } else {
        // gemm: 128-row tile, 1024 threads, each thread 2 rows x 4 cols
        float* Xs = (float*)smem;            // [128][68] = 34816 B (pad: 2-way alias free)
        float* Ws = (float*)(smem + 34816);  // [64][64]  = 16384 B
        ((float4*)Ws)[t] = ((const float4*)Wm)[t];  // 1024 float4 = all of W
        const int n0 = (b - HIST_BLOCKS) * GEMM_TILE;
#pragma unroll
        for (int i2 = 0; i2 < 2; ++i2) {
            int f = t + i2 * 1024;           // 0..2047 float4s
            int r = f >> 4, c = (f & 15) << 2;
            float4 v = make_float4(0.f, 0.f, 0.f, 0.f);
            if (n0 + r < N_NODES) v = ((const float4*)x)[(size_t)n0 * 16 + f];
            float* dp = Xs + r * 68 + c;
            dp[0] = v.x; dp[1] = v.y; dp[2] = v.z; dp[3] = v.w;
        }
        __syncthreads();
        const int tx = t & 15, ty = t >> 4;  // ty 0..63 -> rows 2*ty, 2*ty+1
        float acc[2][4] = {};
#pragma unroll
        for (int k = 0; k < D; ++k) {
            float a0 = Xs[(ty * 2) * 68 + k];
            float a1 = Xs[(ty * 2 + 1) * 68 + k];
            const float* wr = Ws + k * 64 + tx * 4;
#pragma unroll
            for (int jj = 0; jj < 4; ++jj) {
                float bb = wr[jj];
                acc[0][jj] = fmaf(a0, bb, acc[0][jj]);
                acc[1][jj] = fmaf(a1, bb, acc[1][jj]);
            }
        }
#pragma unroll
        for (int i2 = 0; i2 < 2; ++i2) {
            int n = n0 + ty * 2 + i2;
            if (n < N_NODES) {
                ushort4 v;
                v.x = f2bf(acc[i2][0]); v.y = f2bf(acc[i2][1]);
                v.z = f2bf(acc[i2][2]); v.w = f2bf(acc[i2][3]);
                *(ushort4*)(h + (size_t)n * D + tx * 4) = v;
            }
        }
    }
}

// ---- 2. reduce + block scan + inline bs8 emission ----
__global__ __launch_bounds__(256) void reduce_scan_kernel(const unsigned* __restrict__ bh,
                                                          float* __restrict__ dis,
                                                          int* __restrict__ offs_local,
                                                          int* __restrict__ partials,
                                                          unsigned char* __restrict__ bs8) {
    int t = threadIdx.x;
    int i = blockIdx.x * 256 + t;
    unsigned cl = 0;
    if (i < N_NODES) {
        const int w = i >> 2;
        const unsigned sh = 8 * (i & 3);
        const unsigned* prow = bh + w;
        unsigned dl = 0;
#pragma unroll
        for (int g = 0; g < 4; ++g) {
            unsigned vr[16];
#pragma unroll
            for (int k = 0; k < 16; ++k) vr[k] = prow[(size_t)(g * 16 + k) * PACK8];
#pragma unroll
            for (int k = 0; k < 16; ++k) dl += (vr[k] >> sh) & 0xffu;
        }
        dis[i] = rsqrtf((float)dl + 1.0f);  // +1 self loop
        const unsigned* pcol = bh + (size_t)B_SLICE * PACK8 + w;
#pragma unroll
        for (int g = 0; g < 4; ++g) {
            unsigned vr[16];
#pragma unroll
            for (int k = 0; k < 16; ++k) vr[k] = pcol[(size_t)(g * 16 + k) * PACK8];
#pragma unroll
            for (int k = 0; k < 16; ++k) {
                bs8[(size_t)(g * 16 + k) * N_NODES + i] = (unsigned char)cl;  // rel start
                cl += (vr[k] >> sh) & 0xffu;
            }
        }
    }
    __shared__ int s[256];
    s[t] = (int)cl;
    __syncthreads();
    for (int d = 1; d < 256; d <<= 1) {
        int u = (t >= d) ? s[t - d] : 0;
        __syncthreads();
        s[t] += u;
        __syncthreads();
    }
    if (i < N_NODES) offs_local[i] = s[t] - (int)cl;
    if (t == 255) partials[blockIdx.x] = s[t];
}

// ---- 3. tiny offs kernel: redundant partials scan + absolute offs + sentinel ----
__global__ __launch_bounds__(256) void offs_kernel(const int* __restrict__ offs_local,
                                                   const int* __restrict__ partials,
                                                   int* __restrict__ offs) {
    __shared__ int pref[256];
    int t = threadIdx.x;
    int v = (t < NB_SCAN) ? partials[t] : 0;
    pref[t] = v;
    __syncthreads();
    for (int d = 1; d < 256; d <<= 1) {
        int u = (t >= d) ? pref[t - d] : 0;
        __syncthreads();
        pref[t] += u;
        __syncthreads();
    }
    int ex = pref[t] - v;
    __syncthreads();
    pref[t] = ex;
    __syncthreads();
    int i = blockIdx.x * 256 + t;
    if (i < N_NODES) offs[i] = pref[blockIdx.x] + offs_local[i];
    if (i == 0) offs[N_NODES] = N_EDGES;  // sentinel
}

// ---- 4. deterministic bucket: csr = {row, norm}, LDS fetch-add ----
__global__ __launch_bounds__(1024) void bucket_det_kernel(const int* __restrict__ ei,
                                                          const int* __restrict__ offs,
                                                          const unsigned char* __restrict__ bs8,
                                                          const float* __restrict__ dis,
                                                          int2* __restrict__ csr) {
    __shared__ unsigned pos[QUAR];  // 50 KB
    const int s = blockIdx.x >> 2;
    const int q = blockIdx.x & 3;
    const int c0 = q * QUAR;
    const int* offq = offs + c0;
    const unsigned char* relq = bs8 + (size_t)s * N_NODES + c0;
    for (int w = threadIdx.x; w < QUAR; w += 1024)
        pos[w] = (unsigned)offq[w] + relq[w];
    __syncthreads();
    const int* rowp = ei + s * SLICE;
    const int* colp = ei + N_EDGES + s * SLICE;
    for (int i = threadIdx.x; i < SLICE; i += 1024) {
        int c = colp[i];
        if (c >= c0 && c < c0 + QUAR) {
            int r = rowp[i];
            unsigned p = atomicAdd(&pos[c - c0], 1u);  // LDS atomic
            float norm = dis[r] * dis[c];
            csr[p] = make_int2(r, __float_as_int(norm));
        }
    }
}

// ---- 5. gather: wave per node, scalar int2 csr loads, MLP 8, bf16 h ----
__global__ __launch_bounds__(256) void gather_kernel(const int* __restrict__ offs,
                                                     const int2* __restrict__ csr,
                                                     const unsigned short* __restrict__ h,
                                                     const float* __restrict__ dis,
                                                     const float* __restrict__ bias,
                                                     float* __restrict__ out) {
    int wave = threadIdx.x >> 6;
    int j = threadIdx.x & 63;
    int n = blockIdx.x * 4 + wave;
    if (n >= N_NODES) return;

    float dn = dis[n];
    float a[8];
    a[0] = bf2f(h[(size_t)n * D + j]) * dn * dn;  // self loop
#pragma unroll
    for (int k = 1; k < 8; ++k) a[k] = 0.f;

    // wave-uniform (SGPR) csr addressing -> scalar loads, free broadcast
    int beg = __builtin_amdgcn_readfirstlane(offs[n]);
    int m   = __builtin_amdgcn_readfirstlane(offs[n + 1]) - beg;
    const int2* p = csr + beg;

    int i = 0;
    for (; i + 8 <= m; i += 8) {
        int2 e[8];
#pragma unroll
        for (int k = 0; k < 8; ++k) e[k] = p[i + k];
        float v[8];
#pragma unroll
        for (int k = 0; k < 8; ++k) v[k] = bf2f(h[(size_t)e[k].x * D + j]);  // 8 in flight
#pragma unroll
        for (int k = 0; k < 8; ++k) a[k] = fmaf(v[k], __int_as_float(e[k].y), a[k]);
    }
    for (; i + 4 <= m; i += 4) {
        int2 e0 = p[i], e1 = p[i + 1], e2 = p[i + 2], e3 = p[i + 3];
        a[0] = fmaf(bf2f(h[(size_t)e0.x * D + j]), __int_as_float(e0.y), a[0]);
        a[1] = fmaf(bf2f(h[(size_t)e1.x * D + j]), __int_as_float(e1.y), a[1]);
        a[2] = fmaf(bf2f(h[(size_t)e2.x * D + j]), __int_as_float(e2.y), a[2]);
        a[3] = fmaf(bf2f(h[(size_t)e3.x * D + j]), __int_as_float(e3.y), a[3]);
    }
    for (; i < m; ++i) {
        int2 e = p[i];
        a[1] = fmaf(bf2f(h[(size_t)e.x * D + j]), __int_as_float(e.y), a[1]);
    }
    float tot = ((a[0] + a[1]) + (a[2] + a[3])) + ((a[4] + a[5]) + (a[6] + a[7]));
    out[(size_t)n * D + j] = tot + bias[j];
}

// ======================= fallback (atomic) build path =======================

__global__ void hist_kernel(const int* __restrict__ row, const int* __restrict__ col,
                            int* __restrict__ degi, int* __restrict__ cnt) {
    int e = blockIdx.x * blockDim.x + threadIdx.x;
    if (e < N_EDGES) {
        atomicAdd(&degi[row[e]], 1);
        atomicAdd(&cnt[col[e]], 1);
    }
}

__global__ void dis_kernel(int* __restrict__ degi) {
    int i = blockIdx.x * blockDim.x + threadIdx.x;
    if (i < N_NODES) {
        float d = (float)degi[i] + 1.0f;
        ((float*)degi)[i] = rsqrtf(d);
    }
}

__global__ void bucket_fb_kernel(const int* __restrict__ row, const int* __restrict__ col,
                                 const int* __restrict__ offs, int* __restrict__ cur,
                                 const float* __restrict__ dis, int2* __restrict__ csr) {
    int e = blockIdx.x * blockDim.x + threadIdx.x;
    if (e < N_EDGES) {
        int r = row[e], c = col[e];
        int pos = offs[c] + atomicAdd(&cur[c], 1);
        csr[pos] = make_int2(r, __float_as_int(dis[r] * dis[c]));
    }
}

__global__ void block_scan_kernel(const int* __restrict__ cnt, int* __restrict__ offs,
                                  int* __restrict__ partials) {
    __shared__ int s[256];
    int t = threadIdx.x;
    int i = blockIdx.x * 256 + t;
    int v = (i < N_NODES) ? cnt[i] : 0;
    s[t] = v;
    __syncthreads();
    for (int d = 1; d < 256; d <<= 1) {
        int u = (t >= d) ? s[t - d] : 0;
        __syncthreads();
        s[t] += u;
        __syncthreads();
    }
    if (i < N_NODES) offs[i] = s[t] - v;
    if (t == 255) partials[blockIdx.x] = s[t];
}

__global__ void scan_partials_kernel(int* __restrict__ partials) {
    __shared__ int s[256];
    int t = threadIdx.x;
    int v = (t < NB_SCAN) ? partials[t] : 0;
    s[t] = v;
    __syncthreads();
    for (int d = 1; d < 256; d <<= 1) {
        int u = (t >= d) ? s[t - d] : 0;
        __syncthreads();
        s[t] += u;
        __syncthreads();
    }
    if (t < NB_SCAN) partials[t] = s[t] - v;
}

__global__ void add_off_kernel(int* __restrict__ offs, const int* __restrict__ partials) {
    int i = blockIdx.x * 256 + threadIdx.x;
    if (i < N_NODES) offs[i] += partials[blockIdx.x];
    if (i == 0) offs[N_NODES] = N_EDGES;
}

__global__ __launch_bounds__(256) void gemm_fb_kernel(const float* __restrict__ x,
                                                      const float* __restrict__ W,
                                                      unsigned short* __restrict__ h) {
    __shared__ float Xs[64][68];
    __shared__ float Ws[64][64];
    int t = threadIdx.x;
    int n0 = blockIdx.x * 64;
    const float4* W4 = (const float4*)W;
    float4* Ws4 = (float4*)Ws;
#pragma unroll
    for (int i = 0; i < 4; ++i) Ws4[t + i * 256] = W4[t + i * 256];
    const float4* x4 = (const float4*)(x + (size_t)n0 * D);
#pragma unroll
    for (int i = 0; i < 4; ++i) {
        int f = t + i * 256;
        int r = f >> 4, c = (f & 15) << 2;
        float4 v = make_float4(0.f, 0.f, 0.f, 0.f);
        if (n0 + r < N_NODES) v = x4[f];
        Xs[r][c] = v.x; Xs[r][c + 1] = v.y; Xs[r][c + 2] = v.z; Xs[r][c + 3] = v.w;
    }
    __syncthreads();
    int tx = t & 15, ty = t >> 4;
    float acc[4][4] = {};
#pragma unroll
    for (int k = 0; k < D; ++k) {
        float a[4], bb[4];
#pragma unroll
        for (int i = 0; i < 4; ++i) a[i] = Xs[ty * 4 + i][k];
#pragma unroll
        for (int jj = 0; jj < 4; ++jj) bb[jj] = Ws[k][tx * 4 + jj];
#pragma unroll
        for (int i = 0; i < 4; ++i)
#pragma unroll
            for (int jj = 0; jj < 4; ++jj)
                acc[i][jj] = fmaf(a[i], bb[jj], acc[i][jj]);
    }
#pragma unroll
    for (int i = 0; i < 4; ++i) {
        int r = ty * 4 + i;
        if (n0 + r < N_NODES) {
            ushort4 v;
            v.x = f2bf(acc[i][0]); v.y = f2bf(acc[i][1]);
            v.z = f2bf(acc[i][2]); v.w = f2bf(acc[i][3]);
            *(ushort4*)(h + (size_t)(n0 + r) * D + tx * 4) = v;
        }
    }
}

// ======================= launch =======================

extern "C" void kernel_launch(void* const* d_in, const int* in_sizes, int n_in,
                              void* d_out, int out_size, void* d_ws, size_t ws_size,
                              hipStream_t stream) {
    const float* x    = (const float*)d_in[0];
    const int*   ei   = (const int*)d_in[1];
    const float* W    = (const float*)d_in[2];
    const float* bias = (const float*)d_in[3];
    float* out = (float*)d_out;

    // workspace layout (bytes):
    //   [0        ..   200000)  dis / degi (fallback)
    //   [200000   ..   400064)  offs (N+1 ints)
    //   [400064   ..   600064)  offs_local / cnt (fallback)
    //   [600064   ..   800064)  cur (fallback only)
    //   [800064   ..   801088)  partials
    //   [801088   ..  7201088)  csr (800000 x int2)
    //   [7201088  .. 13601088)  h (50000 x 64 bf16)
    //   [13601088 .. 20001088)  bh (128 x 12500 u32, u8-packed)
    //   [20001088 .. 23201088)  bs8 (64 x 50000 u8, relative)
    char* ws = (char*)d_ws;
    float*          dis      = (float*)(ws + 0);
    int*            offs     = (int*)(ws + 200000);
    int*            offs_loc = (int*)(ws + 400064);
    int*            cur      = (int*)(ws + 600064);
    int*            partials = (int*)(ws + 800064);
    int2*           csr      = (int2*)(ws + 801088);
    unsigned short* h        = (unsigned short*)(ws + 7201088);
    unsigned*       bh       = (unsigned*)(ws + 13601088);
    unsigned char*  bs8      = (unsigned char*)(ws + 20001088);

    const size_t WS_NEEDED = 23201088;

    if (ws_size >= WS_NEEDED) {
        histgemm_kernel<<<HIST_BLOCKS + NTILES, 1024, 0, stream>>>(ei, x, W, bh, h);
        reduce_scan_kernel<<<NB_SCAN, 256, 0, stream>>>(bh, dis, offs_loc, partials, bs8);
        offs_kernel<<<NB_SCAN, 256, 0, stream>>>(offs_loc, partials, offs);
        bucket_det_kernel<<<4 * B_SLICE, 1024, 0, stream>>>(ei, offs, bs8, dis, csr);
        gather_kernel<<<(N_NODES + 3) / 4, 256, 0, stream>>>(offs, csr, h, dis, bias, out);
    } else {
        const int* row = ei;
        const int* col = ei + N_EDGES;
        int* degi = (int*)dis;
        int* cntf = offs_loc;
        hipMemsetAsync(ws, 0, 800064, stream);
        hist_kernel<<<(N_EDGES + 255) / 256, 256, 0, stream>>>(row, col, degi, cntf);
        dis_kernel<<<(N_NODES + 255) / 256, 256, 0, stream>>>(degi);
        block_scan_kernel<<<NB_SCAN, 256, 0, stream>>>(cntf, offs, partials);
        scan_partials_kernel<<<1, 256, 0, stream>>>(partials);
        add_off_kernel<<<NB_SCAN, 256, 0, stream>>>(offs, partials);
        bucket_fb_kernel<<<(N_EDGES + 255) / 256, 256, 0, stream>>>(row, col, offs, cur, dis, csr);
        gemm_fb_kernel<<<(N_NODES + 63) / 64, 256, 0, stream>>>(x, W, h);
        gather_kernel<<<(N_NODES + 3) / 4, 256, 0, stream>>>(offs, csr, h, dis, bias, out);
    }
}

// Round 11
// 152.189 us; speedup vs baseline: 4.2520x; 2.3912x over previous
//
#include <hip/hip_runtime.h>
#include <hip/hip_bf16.h>

// GCN layer: out[c] = bias + dis[c]*(hs[c] + sum_{r in in(c)} hs[r]),
//            hs = (X @ W) * dis[row]  (bf16), dis = rsqrt(deg+1).
// N=50000, E=800000, D=64, fp32 in/out.
// R11: back to R8's proven 6-kernel shape (R9/R10 lesson: branchy 1024-thread
//      fused kernels get VGPR-capped to 64 and spill ~500MB of scratch).
//      Deltas vs R8: (a) colscan gone -- reduce_scan emits bs8 inline + tiny
//      offs kernel; (b) gather loads uint (2 bf16) per lane, half-wave per
//      edge: 2 h-rows per load instruction, cross-half combine via shfl.

constexpr int N_NODES = 50000;
constexpr int N_EDGES = 800000;
constexpr int D = 64;
constexpr int NB_SCAN = (N_NODES + 255) / 256;  // 196

constexpr int B_SLICE = 64;                  // edge slices
constexpr int SLICE = N_EDGES / B_SLICE;     // 12500 (exact)
constexpr int PACK8 = N_NODES / 4;           // 12500 u32 words (u8 x4)
constexpr int QUAR = N_NODES / 4;            // 12500 nodes per bucket quarter

static __device__ __forceinline__ unsigned short f2bf(float f) {
    unsigned u = __float_as_uint(f);
    unsigned r = (u + 0x7fffu + ((u >> 16) & 1u)) >> 16;  // RNE
    return (unsigned short)r;
}
static __device__ __forceinline__ float bf_lo(unsigned v) {
    return __uint_as_float(v << 16);
}
static __device__ __forceinline__ float bf_hi(unsigned v) {
    return __uint_as_float(v & 0xffff0000u);
}

// ---- 1. per-slice u8-packed histograms (R8's proven kernel) ----
__global__ __launch_bounds__(1024) void hist_priv_kernel(const int* __restrict__ ei,
                                                         unsigned* __restrict__ bh) {
    __shared__ unsigned loc[PACK8];  // 50 KB
    int b = blockIdx.x;
    int s = b & (B_SLICE - 1);
    const int* arr = (b < B_SLICE) ? ei : ei + N_EDGES;
    for (int w = threadIdx.x; w < PACK8; w += 1024) loc[w] = 0;
    __syncthreads();
    const int* p = arr + s * SLICE;
    for (int i = threadIdx.x; i < SLICE; i += 1024) {
        int k = p[i];
        atomicAdd(&loc[k >> 2], 1u << (8 * (k & 3)));  // LDS atomic, ~Poisson(.25)/bin
    }
    __syncthreads();
    unsigned* dst = bh + (size_t)b * PACK8;
    for (int w = threadIdx.x; w < PACK8; w += 1024) dst[w] = loc[w];
}

// ---- 2. reduce + dis + inline bs8 + block-local scan ----
__global__ __launch_bounds__(256) void reduce_scan_kernel(const unsigned* __restrict__ bh,
                                                          float* __restrict__ dis,
                                                          int* __restrict__ offs_local,
                                                          int* __restrict__ partials,
                                                          unsigned char* __restrict__ bs8) {
    int t = threadIdx.x;
    int i = blockIdx.x * 256 + t;
    unsigned cl = 0;
    if (i < N_NODES) {
        const int w = i >> 2;
        const unsigned sh = 8 * (i & 3);
        const unsigned* prow = bh + w;
        unsigned dl = 0;
#pragma unroll
        for (int g = 0; g < 4; ++g) {
            unsigned vr[16];
#pragma unroll
            for (int k = 0; k < 16; ++k) vr[k] = prow[(size_t)(g * 16 + k) * PACK8];
#pragma unroll
            for (int k = 0; k < 16; ++k) dl += (vr[k] >> sh) & 0xffu;
        }
        dis[i] = rsqrtf((float)dl + 1.0f);  // +1 self loop
        const unsigned* pcol = bh + (size_t)B_SLICE * PACK8 + w;
#pragma unroll
        for (int g = 0; g < 4; ++g) {
            unsigned vr[16];
#pragma unroll
            for (int k = 0; k < 16; ++k) vr[k] = pcol[(size_t)(g * 16 + k) * PACK8];
#pragma unroll
            for (int k = 0; k < 16; ++k) {
                bs8[(size_t)(g * 16 + k) * N_NODES + i] = (unsigned char)cl;  // rel start
                cl += (vr[k] >> sh) & 0xffu;
            }
        }
    }
    __shared__ int s[256];
    s[t] = (int)cl;
    __syncthreads();
    for (int d = 1; d < 256; d <<= 1) {
        int u = (t >= d) ? s[t - d] : 0;
        __syncthreads();
        s[t] += u;
        __syncthreads();
    }
    if (i < N_NODES) offs_local[i] = s[t] - (int)cl;
    if (t == 255) partials[blockIdx.x] = s[t];
}

// ---- 3. offs: redundant partials scan + absolute offs + sentinel ----
__global__ __launch_bounds__(256) void offs_kernel(const int* __restrict__ offs_local,
                                                   const int* __restrict__ partials,
                                                   int* __restrict__ offs) {
    __shared__ int pref[256];
    int t = threadIdx.x;
    int v = (t < NB_SCAN) ? partials[t] : 0;
    pref[t] = v;
    __syncthreads();
    for (int d = 1; d < 256; d <<= 1) {
        int u = (t >= d) ? pref[t - d] : 0;
        __syncthreads();
        pref[t] += u;
        __syncthreads();
    }
    int ex = pref[t] - v;
    __syncthreads();
    pref[t] = ex;
    __syncthreads();
    int i = blockIdx.x * 256 + t;
    if (i < N_NODES) offs[i] = pref[blockIdx.x] + offs_local[i];
    if (i == 0) offs[N_NODES] = N_EDGES;  // sentinel
}

// ---- 4. gemm: 64x64 tile, 4x4 reg tile, hs = bf16(h * dis[row]) (R8 proven) ----
__global__ __launch_bounds__(256) void gemm_kernel(const float* __restrict__ x,
                                                   const float* __restrict__ W,
                                                   const float* __restrict__ dis,
                                                   unsigned short* __restrict__ hs) {
    __shared__ float Xs[64][68];  // pad: 2-way max bank alias = free
    __shared__ float Ws[64][64];
    int t = threadIdx.x;
    int n0 = blockIdx.x * 64;

    const float4* W4 = (const float4*)W;
    float4* Ws4 = (float4*)Ws;
#pragma unroll
    for (int i = 0; i < 4; ++i) Ws4[t + i * 256] = W4[t + i * 256];

    const float4* x4 = (const float4*)(x + (size_t)n0 * D);
#pragma unroll
    for (int i = 0; i < 4; ++i) {
        int f = t + i * 256;
        int r = f >> 4, c = (f & 15) << 2;
        float4 v = make_float4(0.f, 0.f, 0.f, 0.f);
        if (n0 + r < N_NODES) v = x4[f];
        Xs[r][c] = v.x; Xs[r][c + 1] = v.y; Xs[r][c + 2] = v.z; Xs[r][c + 3] = v.w;
    }
    __syncthreads();

    int tx = t & 15, ty = t >> 4;
    float acc[4][4] = {};
#pragma unroll
    for (int k = 0; k < D; ++k) {
        float a[4], bb[4];
#pragma unroll
        for (int i = 0; i < 4; ++i) a[i] = Xs[ty * 4 + i][k];
#pragma unroll
        for (int jj = 0; jj < 4; ++jj) bb[jj] = Ws[k][tx * 4 + jj];
#pragma unroll
        for (int i = 0; i < 4; ++i)
#pragma unroll
            for (int jj = 0; jj < 4; ++jj)
                acc[i][jj] = fmaf(a[i], bb[jj], acc[i][jj]);
    }

#pragma unroll
    for (int i = 0; i < 4; ++i) {
        int r = ty * 4 + i;
        if (n0 + r < N_NODES) {
            float dr = dis[n0 + r];
            ushort4 v;
            v.x = f2bf(acc[i][0] * dr); v.y = f2bf(acc[i][1] * dr);
            v.z = f2bf(acc[i][2] * dr); v.w = f2bf(acc[i][3] * dr);
            *(ushort4*)(hs + (size_t)(n0 + r) * D + tx * 4) = v;
        }
    }
}

// ---- 5. deterministic bucket: pos = offs + u8 rel, csr = row only (R8 proven) ----
__global__ __launch_bounds__(1024) void bucket_det_kernel(const int* __restrict__ ei,
                                                          const int* __restrict__ offs,
                                                          const unsigned char* __restrict__ bs8,
                                                          int* __restrict__ csr) {
    __shared__ unsigned pos[QUAR];  // 50 KB
    const int s = blockIdx.x >> 2;
    const int q = blockIdx.x & 3;
    const int c0 = q * QUAR;
    const int* offq = offs + c0;
    const unsigned char* relq = bs8 + (size_t)s * N_NODES + c0;
    for (int w = threadIdx.x; w < QUAR; w += 1024)
        pos[w] = (unsigned)offq[w] + relq[w];
    __syncthreads();
    const int* rowp = ei + s * SLICE;
    const int* colp = ei + N_EDGES + s * SLICE;
    for (int i = threadIdx.x; i < SLICE; i += 1024) {
        int c = colp[i];
        if (c >= c0 && c < c0 + QUAR) {
            unsigned p = atomicAdd(&pos[c - c0], 1u);  // LDS atomic
            csr[p] = rowp[i];
        }
    }
}

// ---- 6. gather: wave per node, uint (2xbf16) per lane, half-wave per edge ----
// Lanes 0-31 process even-position edges, 32-63 odd: one wave load = TWO h rows
// (256B), halving issued load instructions vs the 1-row scheme.
__global__ __launch_bounds__(256) void gather_kernel(const int* __restrict__ offs,
                                                     const int* __restrict__ csr,
                                                     const unsigned* __restrict__ hs32,
                                                     const float* __restrict__ dis,
                                                     const float* __restrict__ bias,
                                                     float* __restrict__ out) {
    const int wave = threadIdx.x >> 6;
    const int lane = threadIdx.x & 63;
    const int half = lane >> 5;   // 0: even edges, 1: odd edges
    const int jj = lane & 31;     // uint index in row -> features 2jj, 2jj+1
    const int n = blockIdx.x * 4 + wave;
    if (n >= N_NODES) return;

    float aLo[4], aHi[4];
#pragma unroll
    for (int k = 0; k < 4; ++k) { aLo[k] = 0.f; aHi[k] = 0.f; }
    {   // self loop, counted once (half 0)
        unsigned sv = hs32[(size_t)n * 32 + jj];
        if (half == 0) { aLo[0] = bf_lo(sv); aHi[0] = bf_hi(sv); }
    }

    const int beg = __builtin_amdgcn_readfirstlane(offs[n]);
    const int m   = __builtin_amdgcn_readfirstlane(offs[n + 1]) - beg;
    const int* p = csr + beg;  // SGPR base -> scalar loads, free broadcast

    int i = 0;
    for (; i + 16 <= m; i += 16) {   // 8 edges per half, 8 loads in flight
        int r[8];
#pragma unroll
        for (int k = 0; k < 8; ++k) {
            int rA = p[i + 2 * k];
            int rB = p[i + 2 * k + 1];
            r[k] = half ? rB : rA;
        }
        unsigned v[8];
#pragma unroll
        for (int k = 0; k < 8; ++k) v[k] = hs32[(size_t)r[k] * 32 + jj];
#pragma unroll
        for (int k = 0; k < 8; ++k) {
            aLo[k & 3] += bf_lo(v[k]);
            aHi[k & 3] += bf_hi(v[k]);
        }
    }
    for (; i + 2 <= m; i += 2) {
        int rA = p[i], rB = p[i + 1];
        int r = half ? rB : rA;
        unsigned v = hs32[(size_t)r * 32 + jj];
        aLo[1] += bf_lo(v);
        aHi[1] += bf_hi(v);
    }
    if (i < m) {  // odd leftover: half 0 only
        unsigned v = hs32[(size_t)p[i] * 32 + jj];
        if (half == 0) { aLo[2] += bf_lo(v); aHi[2] += bf_hi(v); }
    }

    float tLo = (aLo[0] + aLo[1]) + (aLo[2] + aLo[3]);
    float tHi = (aHi[0] + aHi[1]) + (aHi[2] + aHi[3]);
    // combine the two halves (partner lane = lane ^ 32)
    tLo += __shfl(tLo, lane ^ 32);
    tHi += __shfl(tHi, lane ^ 32);

    if (half == 0) {
        float dn = dis[n];
        float2 bj = ((const float2*)bias)[jj];
        float2 o;
        o.x = fmaf(dn, tLo, bj.x);
        o.y = fmaf(dn, tHi, bj.y);
        ((float2*)out)[(size_t)n * 32 + jj] = o;  // 32 lanes x 8B = 256B coalesced
    }
}

// ======================= fallback (atomic) build path =======================

__global__ void histf_kernel(const int* __restrict__ row, const int* __restrict__ col,
                             int* __restrict__ degi, int* __restrict__ cnt) {
    int e = blockIdx.x * blockDim.x + threadIdx.x;
    if (e < N_EDGES) {
        atomicAdd(&degi[row[e]], 1);
        atomicAdd(&cnt[col[e]], 1);
    }
}

__global__ void disf_kernel(int* __restrict__ degi) {
    int i = blockIdx.x * blockDim.x + threadIdx.x;
    if (i < N_NODES) {
        float d = (float)degi[i] + 1.0f;
        ((float*)degi)[i] = rsqrtf(d);
    }
}

__global__ void block_scan_kernel(const int* __restrict__ cnt, int* __restrict__ offs,
                                  int* __restrict__ partials) {
    __shared__ int s[256];
    int t = threadIdx.x;
    int i = blockIdx.x * 256 + t;
    int v = (i < N_NODES) ? cnt[i] : 0;
    s[t] = v;
    __syncthreads();
    for (int d = 1; d < 256; d <<= 1) {
        int u = (t >= d) ? s[t - d] : 0;
        __syncthreads();
        s[t] += u;
        __syncthreads();
    }
    if (i < N_NODES) offs[i] = s[t] - v;
    if (t == 255) partials[blockIdx.x] = s[t];
}

__global__ void scan_partials_kernel(int* __restrict__ partials) {
    __shared__ int s[256];
    int t = threadIdx.x;
    int v = (t < NB_SCAN) ? partials[t] : 0;
    s[t] = v;
    __syncthreads();
    for (int d = 1; d < 256; d <<= 1) {
        int u = (t >= d) ? s[t - d] : 0;
        __syncthreads();
        s[t] += u;
        __syncthreads();
    }
    if (t < NB_SCAN) partials[t] = s[t] - v;
}

__global__ void add_off_kernel(int* __restrict__ offs, const int* __restrict__ partials) {
    int i = blockIdx.x * 256 + threadIdx.x;
    if (i < N_NODES) offs[i] += partials[blockIdx.x];
    if (i == 0) offs[N_NODES] = N_EDGES;
}

__global__ void bucket_fb_kernel(const int* __restrict__ row, const int* __restrict__ col,
                                 const int* __restrict__ offs, int* __restrict__ cur,
                                 int* __restrict__ csr) {
    int e = blockIdx.x * blockDim.x + threadIdx.x;
    if (e < N_EDGES) {
        int c = col[e];
        int pos = offs[c] + atomicAdd(&cur[c], 1);
        csr[pos] = row[e];
    }
}

// ======================= launch =======================

extern "C" void kernel_launch(void* const* d_in, const int* in_sizes, int n_in,
                              void* d_out, int out_size, void* d_ws, size_t ws_size,
                              hipStream_t stream) {
    const float* x    = (const float*)d_in[0];
    const int*   ei   = (const int*)d_in[1];
    const float* W    = (const float*)d_in[2];
    const float* bias = (const float*)d_in[3];
    float* out = (float*)d_out;

    // workspace layout (bytes):
    //   [0        ..   200000)  dis / degi (fallback)
    //   [200000   ..   400064)  offs (N+1 ints)
    //   [400064   ..   600064)  offs_local / cnt (fallback)
    //   [600064   ..   800064)  cur (fallback only)
    //   [800064   ..   801088)  partials
    //   [801088   ..  4001088)  csr (800000 x int)
    //   [4001088  .. 10401088)  hs (50000 x 64 bf16)
    //   [10401088 .. 16801088)  bh (128 x 12500 u32, u8-packed)
    //   [16801088 .. 20001088)  bs8 (64 x 50000 u8, relative)
    char* ws = (char*)d_ws;
    float*          dis      = (float*)(ws + 0);
    int*            offs     = (int*)(ws + 200000);
    int*            offs_loc = (int*)(ws + 400064);
    int*            cur      = (int*)(ws + 600064);
    int*            partials = (int*)(ws + 800064);
    int*            csr      = (int*)(ws + 801088);
    unsigned short* hs       = (unsigned short*)(ws + 4001088);
    unsigned*       bh       = (unsigned*)(ws + 10401088);
    unsigned char*  bs8      = (unsigned char*)(ws + 16801088);

    const size_t WS_NEEDED = 20001088;

    if (ws_size >= WS_NEEDED) {
        hist_priv_kernel<<<2 * B_SLICE, 1024, 0, stream>>>(ei, bh);
        reduce_scan_kernel<<<NB_SCAN, 256, 0, stream>>>(bh, dis, offs_loc, partials, bs8);
        offs_kernel<<<NB_SCAN, 256, 0, stream>>>(offs_loc, partials, offs);
        gemm_kernel<<<(N_NODES + 63) / 64, 256, 0, stream>>>(x, W, dis, hs);
        bucket_det_kernel<<<4 * B_SLICE, 1024, 0, stream>>>(ei, offs, bs8, csr);
        gather_kernel<<<(N_NODES + 3) / 4, 256, 0, stream>>>(offs, csr, (const unsigned*)hs,
                                                             dis, bias, out);
    } else {
        const int* row = ei;
        const int* col = ei + N_EDGES;
        int* degi = (int*)dis;
        int* cntf = offs_loc;
        hipMemsetAsync(ws, 0, 800064, stream);
        histf_kernel<<<(N_EDGES + 255) / 256, 256, 0, stream>>>(row, col, degi, cntf);
        disf_kernel<<<(N_NODES + 255) / 256, 256, 0, stream>>>(degi);
        block_scan_kernel<<<NB_SCAN, 256, 0, stream>>>(cntf, offs, partials);
        scan_partials_kernel<<<1, 256, 0, stream>>>(partials);
        add_off_kernel<<<NB_SCAN, 256, 0, stream>>>(offs, partials);
        gemm_kernel<<<(N_NODES + 63) / 64, 256, 0, stream>>>(x, W, dis, hs);
        bucket_fb_kernel<<<(N_EDGES + 255) / 256, 256, 0, stream>>>(row, col, offs, cur, csr);
        gather_kernel<<<(N_NODES + 3) / 4, 256, 0, stream>>>(offs, csr, (const unsigned*)hs,
                                                             dis, bias, out);
    }
}

// Round 12
// 133.728 us; speedup vs baseline: 4.8390x; 1.1380x over previous
//
#include <hip/hip_runtime.h>
#include <hip/hip_bf16.h>

// GCN layer: out[c] = bias + dis[c]*(hs[c] + sum_{r in in(c)} hs[r]),
//            hs = (X @ W) * dis[row]  (bf16), dis = rsqrt(deg+1).
// N=50000, E=800000, D=64, fp32 in/out.
// R12: gemm was the hidden 46us kernel (VGPR 248 -> 2 waves/SIMD, 8% occupancy,
//      LDS-latency bound). Fix: __launch_bounds__(256,4) + unroll 8 to bound
//      live ranges. Gather reverted to R8's proven scalar-csr MLP-16 form.

constexpr int N_NODES = 50000;
constexpr int N_EDGES = 800000;
constexpr int D = 64;
constexpr int NB_SCAN = (N_NODES + 255) / 256;  // 196

constexpr int B_SLICE = 64;                  // edge slices
constexpr int SLICE = N_EDGES / B_SLICE;     // 12500 (exact)
constexpr int PACK8 = N_NODES / 4;           // 12500 u32 words (u8 x4)
constexpr int QUAR = N_NODES / 4;            // 12500 nodes per bucket quarter

static __device__ __forceinline__ unsigned short f2bf(float f) {
    unsigned u = __float_as_uint(f);
    unsigned r = (u + 0x7fffu + ((u >> 16) & 1u)) >> 16;  // RNE
    return (unsigned short)r;
}
static __device__ __forceinline__ float bf2f(unsigned short s) {
    return __uint_as_float((unsigned)s << 16);
}

// ---- 1. per-slice u8-packed histograms ----
__global__ __launch_bounds__(1024) void hist_priv_kernel(const int* __restrict__ ei,
                                                         unsigned* __restrict__ bh) {
    __shared__ unsigned loc[PACK8];  // 50 KB
    int b = blockIdx.x;
    int s = b & (B_SLICE - 1);
    const int* arr = (b < B_SLICE) ? ei : ei + N_EDGES;
    for (int w = threadIdx.x; w < PACK8; w += 1024) loc[w] = 0;
    __syncthreads();
    const int* p = arr + s * SLICE;
    for (int i = threadIdx.x; i < SLICE; i += 1024) {
        int k = p[i];
        atomicAdd(&loc[k >> 2], 1u << (8 * (k & 3)));  // LDS atomic, ~Poisson(.25)/bin
    }
    __syncthreads();
    unsigned* dst = bh + (size_t)b * PACK8;
    for (int w = threadIdx.x; w < PACK8; w += 1024) dst[w] = loc[w];
}

// ---- 2. reduce + dis + inline bs8 + block-local scan ----
__global__ __launch_bounds__(256) void reduce_scan_kernel(const unsigned* __restrict__ bh,
                                                          float* __restrict__ dis,
                                                          int* __restrict__ offs_local,
                                                          int* __restrict__ partials,
                                                          unsigned char* __restrict__ bs8) {
    int t = threadIdx.x;
    int i = blockIdx.x * 256 + t;
    unsigned cl = 0;
    if (i < N_NODES) {
        const int w = i >> 2;
        const unsigned sh = 8 * (i & 3);
        const unsigned* prow = bh + w;
        unsigned dl = 0;
#pragma unroll
        for (int g = 0; g < 4; ++g) {
            unsigned vr[16];
#pragma unroll
            for (int k = 0; k < 16; ++k) vr[k] = prow[(size_t)(g * 16 + k) * PACK8];
#pragma unroll
            for (int k = 0; k < 16; ++k) dl += (vr[k] >> sh) & 0xffu;
        }
        dis[i] = rsqrtf((float)dl + 1.0f);  // +1 self loop
        const unsigned* pcol = bh + (size_t)B_SLICE * PACK8 + w;
#pragma unroll
        for (int g = 0; g < 4; ++g) {
            unsigned vr[16];
#pragma unroll
            for (int k = 0; k < 16; ++k) vr[k] = pcol[(size_t)(g * 16 + k) * PACK8];
#pragma unroll
            for (int k = 0; k < 16; ++k) {
                bs8[(size_t)(g * 16 + k) * N_NODES + i] = (unsigned char)cl;  // rel start
                cl += (vr[k] >> sh) & 0xffu;
            }
        }
    }
    __shared__ int s[256];
    s[t] = (int)cl;
    __syncthreads();
    for (int d = 1; d < 256; d <<= 1) {
        int u = (t >= d) ? s[t - d] : 0;
        __syncthreads();
        s[t] += u;
        __syncthreads();
    }
    if (i < N_NODES) offs_local[i] = s[t] - (int)cl;
    if (t == 255) partials[blockIdx.x] = s[t];
}

// ---- 3. offs: redundant partials scan + absolute offs + sentinel ----
__global__ __launch_bounds__(256) void offs_kernel(const int* __restrict__ offs_local,
                                                   const int* __restrict__ partials,
                                                   int* __restrict__ offs) {
    __shared__ int pref[256];
    int t = threadIdx.x;
    int v = (t < NB_SCAN) ? partials[t] : 0;
    pref[t] = v;
    __syncthreads();
    for (int d = 1; d < 256; d <<= 1) {
        int u = (t >= d) ? pref[t - d] : 0;
        __syncthreads();
        pref[t] += u;
        __syncthreads();
    }
    int ex = pref[t] - v;
    __syncthreads();
    pref[t] = ex;
    __syncthreads();
    int i = blockIdx.x * 256 + t;
    if (i < N_NODES) offs[i] = pref[blockIdx.x] + offs_local[i];
    if (i == 0) offs[N_NODES] = N_EDGES;  // sentinel
}

// ---- 4. gemm: 64x64 tile, 4x4 reg tile, hs = bf16(h*dis[row]) ----
// __launch_bounds__(256,4): cap ~128 VGPR -> 4 waves/SIMD (was 248 VGPR / 2 waves
// / 8% occupancy / 46us). unroll 8 bounds LDS-load live ranges.
__global__ __launch_bounds__(256, 4) void gemm_kernel(const float* __restrict__ x,
                                                      const float* __restrict__ W,
                                                      const float* __restrict__ dis,
                                                      unsigned short* __restrict__ hs) {
    __shared__ float Xs[64][68];  // pad: 2-way max bank alias = free
    __shared__ float Ws[64][64];
    int t = threadIdx.x;
    int n0 = blockIdx.x * 64;

    const float4* W4 = (const float4*)W;
    float4* Ws4 = (float4*)Ws;
#pragma unroll
    for (int i = 0; i < 4; ++i) Ws4[t + i * 256] = W4[t + i * 256];

    const float4* x4 = (const float4*)(x + (size_t)n0 * D);
#pragma unroll
    for (int i = 0; i < 4; ++i) {
        int f = t + i * 256;
        int r = f >> 4, c = (f & 15) << 2;
        float4 v = make_float4(0.f, 0.f, 0.f, 0.f);
        if (n0 + r < N_NODES) v = x4[f];
        Xs[r][c] = v.x; Xs[r][c + 1] = v.y; Xs[r][c + 2] = v.z; Xs[r][c + 3] = v.w;
    }
    __syncthreads();

    int tx = t & 15, ty = t >> 4;
    float acc[4][4] = {};
#pragma unroll 8
    for (int k = 0; k < D; ++k) {
        float a[4], bb[4];
#pragma unroll
        for (int i = 0; i < 4; ++i) a[i] = Xs[ty * 4 + i][k];
#pragma unroll
        for (int jj = 0; jj < 4; ++jj) bb[jj] = Ws[k][tx * 4 + jj];
#pragma unroll
        for (int i = 0; i < 4; ++i)
#pragma unroll
            for (int jj = 0; jj < 4; ++jj)
                acc[i][jj] = fmaf(a[i], bb[jj], acc[i][jj]);
    }

#pragma unroll
    for (int i = 0; i < 4; ++i) {
        int r = ty * 4 + i;
        if (n0 + r < N_NODES) {
            float dr = dis[n0 + r];
            ushort4 v;
            v.x = f2bf(acc[i][0] * dr); v.y = f2bf(acc[i][1] * dr);
            v.z = f2bf(acc[i][2] * dr); v.w = f2bf(acc[i][3] * dr);
            *(ushort4*)(hs + (size_t)(n0 + r) * D + tx * 4) = v;
        }
    }
}

// ---- 5. deterministic bucket: pos = offs + u8 rel, csr = row only ----
__global__ __launch_bounds__(1024) void bucket_det_kernel(const int* __restrict__ ei,
                                                          const int* __restrict__ offs,
                                                          const unsigned char* __restrict__ bs8,
                                                          int* __restrict__ csr) {
    __shared__ unsigned pos[QUAR];  // 50 KB
    const int s = blockIdx.x >> 2;
    const int q = blockIdx.x & 3;
    const int c0 = q * QUAR;
    const int* offq = offs + c0;
    const unsigned char* relq = bs8 + (size_t)s * N_NODES + c0;
    for (int w = threadIdx.x; w < QUAR; w += 1024)
        pos[w] = (unsigned)offq[w] + relq[w];
    __syncthreads();
    const int* rowp = ei + s * SLICE;
    const int* colp = ei + N_EDGES + s * SLICE;
    for (int i = threadIdx.x; i < SLICE; i += 1024) {
        int c = colp[i];
        if (c >= c0 && c < c0 + QUAR) {
            unsigned p = atomicAdd(&pos[c - c0], 1u);  // LDS atomic
            csr[p] = rowp[i];
        }
    }
}

// ---- 6. gather: wave per node, scalar csr loads, MLP 16 (R8 proven form) ----
__global__ __launch_bounds__(256) void gather_kernel(const int* __restrict__ offs,
                                                     const int* __restrict__ csr,
                                                     const unsigned short* __restrict__ hs,
                                                     const float* __restrict__ dis,
                                                     const float* __restrict__ bias,
                                                     float* __restrict__ out) {
    int wave = threadIdx.x >> 6;
    int j = threadIdx.x & 63;
    int n = blockIdx.x * 4 + wave;
    if (n >= N_NODES) return;

    float a[8];
    a[0] = bf2f(hs[(size_t)n * D + j]);  // self loop (dis[n]*h[n])
#pragma unroll
    for (int k = 1; k < 8; ++k) a[k] = 0.f;

    // wave-uniform (SGPR) csr addressing -> scalar loads, free broadcast
    int beg = __builtin_amdgcn_readfirstlane(offs[n]);
    int m   = __builtin_amdgcn_readfirstlane(offs[n + 1]) - beg;
    const int* p = csr + beg;

    int i = 0;
    for (; i + 16 <= m; i += 16) {
        int r[16];
        float v[16];
#pragma unroll
        for (int k = 0; k < 16; ++k) r[k] = p[i + k];
#pragma unroll
        for (int k = 0; k < 16; ++k) v[k] = bf2f(hs[(size_t)r[k] * D + j]);  // 16 in flight
#pragma unroll
        for (int k = 0; k < 16; ++k) a[k & 7] += v[k];
    }
    for (; i + 4 <= m; i += 4) {
        int r0 = p[i], r1 = p[i + 1], r2 = p[i + 2], r3 = p[i + 3];
        a[0] += bf2f(hs[(size_t)r0 * D + j]);
        a[1] += bf2f(hs[(size_t)r1 * D + j]);
        a[2] += bf2f(hs[(size_t)r2 * D + j]);
        a[3] += bf2f(hs[(size_t)r3 * D + j]);
    }
    for (; i < m; ++i) a[1] += bf2f(hs[(size_t)p[i] * D + j]);
    float tot = ((a[0] + a[1]) + (a[2] + a[3])) + ((a[4] + a[5]) + (a[6] + a[7]));
    out[(size_t)n * D + j] = fmaf(dis[n], tot, bias[j]);
}

// ======================= fallback (atomic) build path =======================

__global__ void histf_kernel(const int* __restrict__ row, const int* __restrict__ col,
                             int* __restrict__ degi, int* __restrict__ cnt) {
    int e = blockIdx.x * blockDim.x + threadIdx.x;
    if (e < N_EDGES) {
        atomicAdd(&degi[row[e]], 1);
        atomicAdd(&cnt[col[e]], 1);
    }
}

__global__ void disf_kernel(int* __restrict__ degi) {
    int i = blockIdx.x * blockDim.x + threadIdx.x;
    if (i < N_NODES) {
        float d = (float)degi[i] + 1.0f;
        ((float*)degi)[i] = rsqrtf(d);
    }
}

__global__ void block_scan_kernel(const int* __restrict__ cnt, int* __restrict__ offs,
                                  int* __restrict__ partials) {
    __shared__ int s[256];
    int t = threadIdx.x;
    int i = blockIdx.x * 256 + t;
    int v = (i < N_NODES) ? cnt[i] : 0;
    s[t] = v;
    __syncthreads();
    for (int d = 1; d < 256; d <<= 1) {
        int u = (t >= d) ? s[t - d] : 0;
        __syncthreads();
        s[t] += u;
        __syncthreads();
    }
    if (i < N_NODES) offs[i] = s[t] - v;
    if (t == 255) partials[blockIdx.x] = s[t];
}

__global__ void scan_partials_kernel(int* __restrict__ partials) {
    __shared__ int s[256];
    int t = threadIdx.x;
    int v = (t < NB_SCAN) ? partials[t] : 0;
    s[t] = v;
    __syncthreads();
    for (int d = 1; d < 256; d <<= 1) {
        int u = (t >= d) ? s[t - d] : 0;
        __syncthreads();
        s[t] += u;
        __syncthreads();
    }
    if (t < NB_SCAN) partials[t] = s[t] - v;
}

__global__ void add_off_kernel(int* __restrict__ offs, const int* __restrict__ partials) {
    int i = blockIdx.x * 256 + threadIdx.x;
    if (i < N_NODES) offs[i] += partials[blockIdx.x];
    if (i == 0) offs[N_NODES] = N_EDGES;
}

__global__ void bucket_fb_kernel(const int* __restrict__ row, const int* __restrict__ col,
                                 const int* __restrict__ offs, int* __restrict__ cur,
                                 int* __restrict__ csr) {
    int e = blockIdx.x * blockDim.x + threadIdx.x;
    if (e < N_EDGES) {
        int c = col[e];
        int pos = offs[c] + atomicAdd(&cur[c], 1);
        csr[pos] = row[e];
    }
}

// ======================= launch =======================

extern "C" void kernel_launch(void* const* d_in, const int* in_sizes, int n_in,
                              void* d_out, int out_size, void* d_ws, size_t ws_size,
                              hipStream_t stream) {
    const float* x    = (const float*)d_in[0];
    const int*   ei   = (const int*)d_in[1];
    const float* W    = (const float*)d_in[2];
    const float* bias = (const float*)d_in[3];
    float* out = (float*)d_out;

    // workspace layout (bytes):
    //   [0        ..   200000)  dis / degi (fallback)
    //   [200000   ..   400064)  offs (N+1 ints)
    //   [400064   ..   600064)  offs_local / cnt (fallback)
    //   [600064   ..   800064)  cur (fallback only)
    //   [800064   ..   801088)  partials
    //   [801088   ..  4001088)  csr (800000 x int)
    //   [4001088  .. 10401088)  hs (50000 x 64 bf16)
    //   [10401088 .. 16801088)  bh (128 x 12500 u32, u8-packed)
    //   [16801088 .. 20001088)  bs8 (64 x 50000 u8, relative)
    char* ws = (char*)d_ws;
    float*          dis      = (float*)(ws + 0);
    int*            offs     = (int*)(ws + 200000);
    int*            offs_loc = (int*)(ws + 400064);
    int*            cur      = (int*)(ws + 600064);
    int*            partials = (int*)(ws + 800064);
    int*            csr      = (int*)(ws + 801088);
    unsigned short* hs       = (unsigned short*)(ws + 4001088);
    unsigned*       bh       = (unsigned*)(ws + 10401088);
    unsigned char*  bs8      = (unsigned char*)(ws + 16801088);

    const size_t WS_NEEDED = 20001088;

    if (ws_size >= WS_NEEDED) {
        hist_priv_kernel<<<2 * B_SLICE, 1024, 0, stream>>>(ei, bh);
        reduce_scan_kernel<<<NB_SCAN, 256, 0, stream>>>(bh, dis, offs_loc, partials, bs8);
        offs_kernel<<<NB_SCAN, 256, 0, stream>>>(offs_loc, partials, offs);
        gemm_kernel<<<(N_NODES + 63) / 64, 256, 0, stream>>>(x, W, dis, hs);
        bucket_det_kernel<<<4 * B_SLICE, 1024, 0, stream>>>(ei, offs, bs8, csr);
        gather_kernel<<<(N_NODES + 3) / 4, 256, 0, stream>>>(offs, csr, hs, dis, bias, out);
    } else {
        const int* row = ei;
        const int* col = ei + N_EDGES;
        int* degi = (int*)dis;
        int* cntf = offs_loc;
        hipMemsetAsync(ws, 0, 800064, stream);
        histf_kernel<<<(N_EDGES + 255) / 256, 256, 0, stream>>>(row, col, degi, cntf);
        disf_kernel<<<(N_NODES + 255) / 256, 256, 0, stream>>>(degi);
        block_scan_kernel<<<NB_SCAN, 256, 0, stream>>>(cntf, offs, partials);
        scan_partials_kernel<<<1, 256, 0, stream>>>(partials);
        add_off_kernel<<<NB_SCAN, 256, 0, stream>>>(offs, partials);
        gemm_kernel<<<(N_NODES + 63) / 64, 256, 0, stream>>>(x, W, dis, hs);
        bucket_fb_kernel<<<(N_EDGES + 255) / 256, 256, 0, stream>>>(row, col, offs, cur, csr);
        gather_kernel<<<(N_NODES + 3) / 4, 256, 0, stream>>>(offs, csr, hs, dis, bias, out);
    }
}